// Round 19
// baseline (20.208 us; speedup 1.0000x reference)
//
#include <hip/hip_runtime.h>
#include <math.h>

#define NG  8
#define DH  8
#define NCP 4     // channel pairs
#define KS  7
#define PAD 3
#define TH  16    // tile rows
#define OW  2     // outputs per thread along W
#define TPH 22    // padded tile rows
#define RSTW 40   // LDS row stride in h2-words
#define PLW  (TPH * RSTW)   // 880 words per cp-plane
#define CH  64
#define HH  64
#define WW  64

typedef __fp16 h2v __attribute__((ext_vector_type(2)));
typedef __fp16 h4v __attribute__((ext_vector_type(4)));
typedef __fp16 h8v __attribute__((ext_vector_type(8)));

#if __has_builtin(__builtin_amdgcn_exp2f)
#define EXP2(x) __builtin_amdgcn_exp2f(x)
#else
#define EXP2(x) exp2f(x)
#endif

__device__ __forceinline__ int imin(int a, int b) { return a < b ? a : b; }
__device__ __forceinline__ int imax(int a, int b) { return a > b ? a : b; }

// ---- staging helpers (R17-verified quad scheme; w0 is the tile col base) ----
// thread job (half,pair,row): load x cols (w0-4+4k .. w0-1+4k), k=5*half+u, u=0..5
__device__ __forceinline__ void stage_load(const float* xb, int hb, int w0,
                                           int half, int pair, int row,
                                           float4* qa, float4* qb) {
  const int yy  = hb + row - PAD;
  const bool yok = (yy >= 0) & (yy < HH);
  const int  cy  = imin(imax(yy, 0), HH - 1);
  const float* pl0 = xb + ((size_t)(2 * pair) * HH + cy) * WW;
  const float* pl1 = pl0 + HH * WW;
  const float4 Z = make_float4(0.f, 0.f, 0.f, 0.f);
  #pragma unroll
  for (int u = 0; u < 6; u++) {
    int qc = w0 - 4 + 4 * (5 * half + u);
    bool qin = yok & (qc >= 0) & (qc <= WW - 4);
    int qs = qin ? qc : 0;
    float4 A = *(const float4*)(pl0 + qs);
    float4 B = *(const float4*)(pl1 + qs);
    qa[u] = qin ? A : Z;
    qb[u] = qin ? B : Z;
  }
}

__device__ __forceinline__ void stage_write(h2v* xsb, int half, int pair, int row,
                                            const float4* qa, const float4* qb) {
  #pragma unroll
  for (int c = 0; c < 5; c++) {
    h2v e0 = __builtin_amdgcn_cvt_pkrtz(qa[c].y, qb[c].y);
    h2v e1 = __builtin_amdgcn_cvt_pkrtz(qa[c].z, qb[c].z);
    h2v e2 = __builtin_amdgcn_cvt_pkrtz(qa[c].w, qb[c].w);
    h2v e3 = __builtin_amdgcn_cvt_pkrtz(qa[c + 1].x, qb[c + 1].x);
    h8v w8 = { e0.x, e0.y, e1.x, e1.y, e2.x, e2.y, e3.x, e3.y };
    *(h8v*)&xsb[pair * PLW + row * RSTW + 4 * (5 * half + c)] = w8;
  }
}

// ---- R16 compute path, factored (single code copy, called twice) ----
__device__ __attribute__((noinline)) void compute_tile(
    const h2v* xsb, const h2v* swq2, const h2v* swk2,
    const h2v* srel2, const h2v* swv2,
    int tx, int ty, int g, int hb, int w0, int b,
    float* __restrict__ out) {
  // preamble, all fdot2
  h2v  qkh[OW][NCP];
  float rq[OW][KS];
  {
    h2v xc2[OW][NCP];
    #pragma unroll
    for (int o = 0; o < OW; o++)
      #pragma unroll
      for (int cp = 0; cp < NCP; cp++)
        xc2[o][cp] = xsb[cp * PLW + (ty + PAD) * RSTW + (2 * tx + o + PAD)];

    #pragma unroll
    for (int o = 0; o < OW; o++) {
      float q_[DH];
      #pragma unroll
      for (int c = 0; c < DH; c++) {
        float a = 0.f;
        #pragma unroll
        for (int cp = 0; cp < NCP; cp++)
          a = __builtin_amdgcn_fdot2(swq2[c * 4 + cp], xc2[o][cp], a, false);
        q_[c] = a;
      }
      h2v qp[NCP];
      #pragma unroll
      for (int cP = 0; cP < NCP; cP++)
        qp[cP] = __builtin_amdgcn_cvt_pkrtz(q_[2 * cP], q_[2 * cP + 1]);

      float qkt[DH];
      #pragma unroll
      for (int ci = 0; ci < DH; ci++) {
        float a = 0.f;
        #pragma unroll
        for (int cP = 0; cP < NCP; cP++)
          a = __builtin_amdgcn_fdot2(qp[cP], swk2[ci * 4 + cP], a, false);
        qkt[ci] = a;
      }
      #pragma unroll
      for (int cp = 0; cp < NCP; cp++)
        qkh[o][cp] = __builtin_amdgcn_cvt_pkrtz(qkt[2 * cp], qkt[2 * cp + 1]);

      #pragma unroll
      for (int t = 0; t < KS; t++) {
        float a = 0.f;
        #pragma unroll
        for (int cP = 0; cP < NCP; cP++)
          a = __builtin_amdgcn_fdot2(qp[cP], srel2[t * 4 + cP], a, false);
        rq[o][t] = a;
      }
    }
  }

  float s[OW], xa[OW][DH];
  #pragma unroll
  for (int o = 0; o < OW; o++) {
    s[o] = 0.f;
    #pragma unroll
    for (int ci = 0; ci < DH; ci++) xa[o][ci] = 0.f;
  }

#define WINLOOP(DINIT)                                                         \
  _Pragma("unroll")                                                            \
  for (int i = 0; i < KS; i++) {                                               \
    const int wbase = (ty + i) * RSTW + 2 * tx;                                \
    h2v xw[NCP][8];                                                            \
    _Pragma("unroll")                                                          \
    for (int cp = 0; cp < NCP; cp++) {                                         \
      const h4v* bp = (const h4v*)&xsb[cp * PLW + wbase];                      \
      h4v r0 = bp[0], r1 = bp[1], r2 = bp[2], r3 = bp[3];                      \
      xw[cp][0] = __builtin_shufflevector(r0, r0, 0, 1);                       \
      xw[cp][1] = __builtin_shufflevector(r0, r0, 2, 3);                       \
      xw[cp][2] = __builtin_shufflevector(r1, r1, 0, 1);                       \
      xw[cp][3] = __builtin_shufflevector(r1, r1, 2, 3);                       \
      xw[cp][4] = __builtin_shufflevector(r2, r2, 0, 1);                       \
      xw[cp][5] = __builtin_shufflevector(r2, r2, 2, 3);                       \
      xw[cp][6] = __builtin_shufflevector(r3, r3, 0, 1);                       \
      xw[cp][7] = __builtin_shufflevector(r3, r3, 2, 3);                       \
    }                                                                          \
    _Pragma("unroll")                                                          \
    for (int o = 0; o < OW; o++) {                                             \
      float e[KS];                                                             \
      float se = 0.f;                                                          \
      _Pragma("unroll")                                                        \
      for (int j = 0; j < KS; j++) {                                           \
        float d = (DINIT);                                                     \
        _Pragma("unroll")                                                      \
        for (int cp = 0; cp < NCP; cp++)                                       \
          d = __builtin_amdgcn_fdot2(qkh[o][cp], xw[cp][o + j], d, false);     \
        e[j] = EXP2(d);                                                        \
        se += e[j];                                                            \
      }                                                                        \
      s[o] += se;                                                              \
      _Pragma("unroll")                                                        \
      for (int cp = 0; cp < NCP; cp++) {                                       \
        float a0 = xa[o][2 * cp];                                              \
        float a1 = xa[o][2 * cp + 1];                                          \
        _Pragma("unroll")                                                      \
        for (int j = 0; j < KS; j++) {                                         \
          a0 = fmaf(e[j], (float)xw[cp][o + j].x, a0);                         \
          a1 = fmaf(e[j], (float)xw[cp][o + j].y, a1);                         \
        }                                                                      \
        xa[o][2 * cp]     = a0;                                                \
        xa[o][2 * cp + 1] = a1;                                                \
      }                                                                        \
    }                                                                          \
  }

  if (g < 4) { WINLOOP(rq[o][i]) }
  else       { WINLOOP(rq[o][j]) }
#undef WINLOOP

  // epilogue
  h2v xav2[OW][NCP];
  #pragma unroll
  for (int o = 0; o < OW; o++) {
    float inv = 1.0f / s[o];
    #pragma unroll
    for (int cp = 0; cp < NCP; cp++)
      xav2[o][cp] = __builtin_amdgcn_cvt_pkrtz(xa[o][2 * cp] * inv,
                                               xa[o][2 * cp + 1] * inv);
  }

  const int h = hb + ty;
  const int wb = w0 + 2 * tx;
  #pragma unroll
  for (int c = 0; c < DH; c++) {
    float a0 = 0.f, a1 = 0.f;
    #pragma unroll
    for (int cp = 0; cp < NCP; cp++) {
      a0 = __builtin_amdgcn_fdot2(swv2[c * 4 + cp], xav2[0][cp], a0, false);
      a1 = __builtin_amdgcn_fdot2(swv2[c * 4 + cp], xav2[1][cp], a1, false);
    }
    *(float2*)(&out[((size_t)(b * CH + g * DH + c) * HH + h) * WW + wb]) =
        make_float2(a0, a1);
  }
}

__global__ __launch_bounds__(256, 1)
void saconv_kernel(const float* __restrict__ x,
                   const float* __restrict__ wq,
                   const float* __restrict__ wk,
                   const float* __restrict__ wv,
                   const float* __restrict__ relh,
                   const float* __restrict__ relw,
                   float* __restrict__ out) {
  __shared__ h2v xs2[2][NCP * PLW];     // double tile buffer, 28.2 KB
  __shared__ h2v swq2[DH * NCP];
  __shared__ h2v swv2[DH * NCP];
  __shared__ h2v swk2[DH * NCP];        // transposed, sl2e pre-folded
  __shared__ h2v srel2[KS * NCP];       // sl2e pre-folded

  const int tx  = threadIdx.x;          // 0..15
  const int ty  = threadIdx.y;          // 0..15
  const int tid = ty * 16 + tx;
  const int bz  = blockIdx.y;
  const int b   = bz >> 3;
  const int g   = bz & 7;
  const int hb  = blockIdx.x * TH;

  const float sl2e = 0.35355339059327373f * 1.4426950408889634f;

  // ---- stage weights as f16 pairs ----
  if (tid < 32) {
    int c = tid >> 2, cp = tid & 3;
    swq2[tid] = __builtin_amdgcn_cvt_pkrtz(wq[g * 64 + c * 8 + 2 * cp],
                                           wq[g * 64 + c * 8 + 2 * cp + 1]);
  } else if (tid < 64) {
    int t2 = tid - 32;
    int c = t2 >> 2, cp = t2 & 3;
    swv2[t2] = __builtin_amdgcn_cvt_pkrtz(wv[g * 64 + c * 8 + 2 * cp],
                                          wv[g * 64 + c * 8 + 2 * cp + 1]);
  } else if (tid < 96) {
    int t2 = tid - 64;
    int ci = t2 >> 2, cP = t2 & 3;
    swk2[t2] = __builtin_amdgcn_cvt_pkrtz(wk[g * 64 + (2 * cP) * 8 + ci] * sl2e,
                                          wk[g * 64 + (2 * cP + 1) * 8 + ci] * sl2e);
  } else if (tid < 96 + KS * NCP) {
    int t2 = tid - 96;
    int t = t2 >> 2, cP = t2 & 3;
    float a0, a1;
    if (g < 4) {
      a0 = relh[(g * 8 + 2 * cP) * KS + t];
      a1 = relh[(g * 8 + 2 * cP + 1) * KS + t];
    } else {
      a0 = relw[((g - 4) * 8 + 2 * cP) * KS + t];
      a1 = relw[((g - 4) * 8 + 2 * cP + 1) * KS + t];
    }
    srel2[t2] = __builtin_amdgcn_cvt_pkrtz(a0 * sl2e, a1 * sl2e);
  }

  const float* xb = x + (size_t)(b * CH + g * DH) * (HH * WW);
  const bool stager = (tid < 176);
  int half = 0, pair = 0, rowS = 0;
  if (stager) {
    half = tid / 88;
    int rem = tid - half * 88;
    pair = rem / 22;
    rowS = rem - pair * 22;
  }

  // ---- tile A (w0=0): load + write + barrier ----
  {
    float4 qa[6], qb[6];
    if (stager) {
      stage_load(xb, hb, 0, half, pair, rowS, qa, qb);
      stage_write(&xs2[0][0], half, pair, rowS, qa, qb);
    }
  }
  __syncthreads();

  // ---- tile B (w0=32): ISSUE loads now, hide latency under compute A ----
  float4 qa[6], qb[6];
  if (stager)
    stage_load(xb, hb, 32, half, pair, rowS, qa, qb);
  __builtin_amdgcn_sched_barrier(0);   // keep B loads issued before compute A

  compute_tile(&xs2[0][0], swq2, swk2, srel2, swv2, tx, ty, g, hb, 0, b, out);

  // write B (different buffer than A's readers -> no barrier needed before)
  if (stager)
    stage_write(&xs2[1][0], half, pair, rowS, qa, qb);
  __syncthreads();

  compute_tile(&xs2[1][0], swq2, swk2, srel2, swv2, tx, ty, g, hb, 32, b, out);
}

extern "C" void kernel_launch(void* const* d_in, const int* in_sizes, int n_in,
                              void* d_out, int out_size, void* d_ws, size_t ws_size,
                              hipStream_t stream) {
  const float* x    = (const float*)d_in[0];
  // d_in[1] = r, unused by the reference computation
  const float* wq   = (const float*)d_in[2];
  const float* wk   = (const float*)d_in[3];
  const float* wv   = (const float*)d_in[4];
  const float* relh = (const float*)d_in[5];
  const float* relw = (const float*)d_in[6];
  float* out = (float*)d_out;

  const int B = in_sizes[0] / (CH * HH * WW);   // 8
  dim3 grid(HH / TH, B * NG, 1);                // 4 x 64 = 256 blocks, 2 tiles each
  dim3 block(16, 16, 1);                        // 256 threads = 4 waves
  saconv_kernel<<<grid, block, 0, stream>>>(x, wq, wk, wv, relh, relw, out);
}

// Round 20
// 17.004 us; speedup vs baseline: 1.1884x; 1.1884x over previous
//
#include <hip/hip_runtime.h>
#include <math.h>

#define NG  8
#define DH  8
#define NCP 4     // channel pairs
#define KS  7
#define PAD 3
#define TH  16    // tile rows
#define TW  32    // tile cols
#define OW  2     // outputs per thread along W
#define TPH 22    // padded tile rows
#define RSTW 40   // LDS row stride in h2-words (38 cols + 2 pad)
#define PLW  (TPH * RSTW)   // 880 words per cp-plane
#define CH  64
#define HH  64
#define WW  64

typedef __fp16 h2v __attribute__((ext_vector_type(2)));
typedef __fp16 h4v __attribute__((ext_vector_type(4)));

#if __has_builtin(__builtin_amdgcn_exp2f)
#define EXP2(x) __builtin_amdgcn_exp2f(x)
#else
#define EXP2(x) exp2f(x)
#endif

__device__ __forceinline__ int imin(int a, int b) { return a < b ? a : b; }
__device__ __forceinline__ int imax(int a, int b) { return a > b ? a : b; }

__global__ __launch_bounds__(256, 2)   // cap 128 VGPR (R12-proven)
void saconv_kernel(const float* __restrict__ x,
                   const float* __restrict__ wq,
                   const float* __restrict__ wk,
                   const float* __restrict__ wv,
                   const float* __restrict__ relh,
                   const float* __restrict__ relw,
                   float* __restrict__ out) {
  // xs2[cp*PLW + row*RSTW + col] = h2( x[b,g*8+2cp,row',col'], x[b,g*8+2cp+1,row',col'] )
  __shared__ h2v xs2[NCP * PLW];        // 14.1 KB
  __shared__ h2v swq2[DH * NCP];        // [c][cp]  = (wq[c][2cp], wq[c][2cp+1])
  __shared__ h2v swv2[DH * NCP];        // [c][cp]
  __shared__ h2v swk2[DH * NCP];        // [ci][cP] = sl2e*(wk[2cP][ci], wk[2cP+1][ci]) transposed
  __shared__ h2v srel2[KS * NCP];       // [t][cP]  = sl2e*(rel[2cP][t], rel[2cP+1][t])

  const int tx  = threadIdx.x;          // 0..15 (pair of output columns)
  const int ty  = threadIdx.y;          // 0..15 (output row)
  const int tid = ty * 16 + tx;
  const int bz  = blockIdx.z;
  const int b   = bz >> 3;
  const int g   = bz & 7;
  const int h0  = blockIdx.y * TH;
  const int w0  = blockIdx.x * TW;

  const float sl2e = 0.35355339059327373f * 1.4426950408889634f;  // sqrt(1/8)*log2(e)

  // ---- stage weights as f16 pairs (124 items) ----
  if (tid < 32) {
    int c = tid >> 2, cp = tid & 3;
    swq2[tid] = __builtin_amdgcn_cvt_pkrtz(wq[g * 64 + c * 8 + 2 * cp],
                                           wq[g * 64 + c * 8 + 2 * cp + 1]);
  } else if (tid < 64) {
    int t2 = tid - 32;
    int c = t2 >> 2, cp = t2 & 3;
    swv2[t2] = __builtin_amdgcn_cvt_pkrtz(wv[g * 64 + c * 8 + 2 * cp],
                                          wv[g * 64 + c * 8 + 2 * cp + 1]);
  } else if (tid < 96) {
    int t2 = tid - 64;
    int ci = t2 >> 2, cP = t2 & 3;
    swk2[t2] = __builtin_amdgcn_cvt_pkrtz(wk[g * 64 + (2 * cP) * 8 + ci] * sl2e,
                                          wk[g * 64 + (2 * cP + 1) * 8 + ci] * sl2e);
  } else if (tid < 96 + KS * NCP) {
    int t2 = tid - 96;
    int t = t2 >> 2, cP = t2 & 3;
    float a0, a1;
    if (g < 4) {
      a0 = relh[(g * 8 + 2 * cP) * KS + t];
      a1 = relh[(g * 8 + 2 * cP + 1) * KS + t];
    } else {
      a0 = relw[((g - 4) * 8 + 2 * cP) * KS + t];
      a1 = relw[((g - 4) * 8 + 2 * cP + 1) * KS + t];
    }
    srel2[t2] = __builtin_amdgcn_cvt_pkrtz(a0 * sl2e, a1 * sl2e);
  }

  // ---- stage zero-padded x tile as f16 channel-pairs (b64 = 2 cols) ----
  const float* xb = x + (size_t)(b * CH + g * DH) * (HH * WW);
  const int NCHK = NCP * TPH * 19;      // 1672 b64 chunks (cols 0..37)
  #pragma unroll
  for (int kk = 0; kk < 7; kk++) {
    int f = tid + kk * 256;
    if (f < NCHK) {
      int cp  = f / (TPH * 19);
      int r   = f - cp * (TPH * 19);
      int row = r / 19;
      int cc  = r - row * 19;
      int yy  = h0 + row - PAD;
      int cy  = imin(imax(yy, 0), HH - 1);
      bool yok = (yy >= 0) & (yy < HH);
      const float* p0 = xb + ((size_t)(2 * cp) * HH + cy) * WW;
      float v0[2], v1[2];
      #pragma unroll
      for (int e = 0; e < 2; e++) {
        int xx = w0 + 2 * cc + e - PAD;
        int cx = imin(imax(xx, 0), WW - 1);
        bool inb = yok & (xx >= 0) & (xx < WW);
        float a0 = p0[cx];
        float a1 = p0[HH * WW + cx];
        v0[e] = inb ? a0 : 0.0f;
        v1[e] = inb ? a1 : 0.0f;
      }
      h2v pk0 = __builtin_amdgcn_cvt_pkrtz(v0[0], v1[0]);
      h2v pk1 = __builtin_amdgcn_cvt_pkrtz(v0[1], v1[1]);
      h4v w4 = { pk0.x, pk0.y, pk1.x, pk1.y };
      *(h4v*)&xs2[cp * PLW + row * RSTW + 2 * cc] = w4;
    }
  }
  __syncthreads();

  // ---- T5: boost this block's compute phase over the co-resident block's staging ----
  __builtin_amdgcn_s_setprio(1);

  // ---- preamble, all fdot2 (R16-verbatim) ----
  h2v  qkh[OW][NCP];
  float rq[OW][KS];
  {
    h2v xc2[OW][NCP];
    #pragma unroll
    for (int o = 0; o < OW; o++)
      #pragma unroll
      for (int cp = 0; cp < NCP; cp++)
        xc2[o][cp] = xs2[cp * PLW + (ty + PAD) * RSTW + (2 * tx + o + PAD)];

    #pragma unroll
    for (int o = 0; o < OW; o++) {
      float q_[DH];
      #pragma unroll
      for (int c = 0; c < DH; c++) {
        float a = 0.f;
        #pragma unroll
        for (int cp = 0; cp < NCP; cp++)
          a = __builtin_amdgcn_fdot2(swq2[c * 4 + cp], xc2[o][cp], a, false);
        q_[c] = a;
      }
      h2v qp[NCP];
      #pragma unroll
      for (int cP = 0; cP < NCP; cP++)
        qp[cP] = __builtin_amdgcn_cvt_pkrtz(q_[2 * cP], q_[2 * cP + 1]);

      float qkt[DH];
      #pragma unroll
      for (int ci = 0; ci < DH; ci++) {
        float a = 0.f;
        #pragma unroll
        for (int cP = 0; cP < NCP; cP++)
          a = __builtin_amdgcn_fdot2(qp[cP], swk2[ci * 4 + cP], a, false);
        qkt[ci] = a;
      }
      #pragma unroll
      for (int cp = 0; cp < NCP; cp++)
        qkh[o][cp] = __builtin_amdgcn_cvt_pkrtz(qkt[2 * cp], qkt[2 * cp + 1]);

      #pragma unroll
      for (int t = 0; t < KS; t++) {
        float a = 0.f;
        #pragma unroll
        for (int cP = 0; cP < NCP; cP++)
          a = __builtin_amdgcn_fdot2(qp[cP], srel2[t * 4 + cP], a, false);
        rq[o][t] = a;
      }
    }
  }

  // ---- window loop (R16-verbatim) ----
  float s[OW], xa[OW][DH];
  #pragma unroll
  for (int o = 0; o < OW; o++) {
    s[o] = 0.f;
    #pragma unroll
    for (int ci = 0; ci < DH; ci++) xa[o][ci] = 0.f;
  }

#define WINLOOP(DINIT)                                                         \
  _Pragma("unroll")                                                            \
  for (int i = 0; i < KS; i++) {                                               \
    const int wbase = (ty + i) * RSTW + 2 * tx;                                \
    h2v xw[NCP][8];                                                            \
    _Pragma("unroll")                                                          \
    for (int cp = 0; cp < NCP; cp++) {                                         \
      const h4v* bp = (const h4v*)&xs2[cp * PLW + wbase];                      \
      h4v r0 = bp[0], r1 = bp[1], r2 = bp[2], r3 = bp[3];                      \
      xw[cp][0] = __builtin_shufflevector(r0, r0, 0, 1);                       \
      xw[cp][1] = __builtin_shufflevector(r0, r0, 2, 3);                       \
      xw[cp][2] = __builtin_shufflevector(r1, r1, 0, 1);                       \
      xw[cp][3] = __builtin_shufflevector(r1, r1, 2, 3);                       \
      xw[cp][4] = __builtin_shufflevector(r2, r2, 0, 1);                       \
      xw[cp][5] = __builtin_shufflevector(r2, r2, 2, 3);                       \
      xw[cp][6] = __builtin_shufflevector(r3, r3, 0, 1);                       \
      xw[cp][7] = __builtin_shufflevector(r3, r3, 2, 3);                       \
    }                                                                          \
    _Pragma("unroll")                                                          \
    for (int o = 0; o < OW; o++) {                                             \
      float e[KS];                                                             \
      float se = 0.f;                                                          \
      _Pragma("unroll")                                                        \
      for (int j = 0; j < KS; j++) {                                           \
        float d = (DINIT);                                                     \
        _Pragma("unroll")                                                      \
        for (int cp = 0; cp < NCP; cp++)                                       \
          d = __builtin_amdgcn_fdot2(qkh[o][cp], xw[cp][o + j], d, false);     \
        e[j] = EXP2(d);                                                        \
        se += e[j];                                                            \
      }                                                                        \
      s[o] += se;                                                              \
      _Pragma("unroll")                                                        \
      for (int cp = 0; cp < NCP; cp++) {                                       \
        float a0 = xa[o][2 * cp];                                              \
        float a1 = xa[o][2 * cp + 1];                                          \
        _Pragma("unroll")                                                      \
        for (int j = 0; j < KS; j++) {                                         \
          a0 = fmaf(e[j], (float)xw[cp][o + j].x, a0);                         \
          a1 = fmaf(e[j], (float)xw[cp][o + j].y, a1);                         \
        }                                                                      \
        xa[o][2 * cp]     = a0;                                                \
        xa[o][2 * cp + 1] = a1;                                                \
      }                                                                        \
    }                                                                          \
  }

  if (g < 4) { WINLOOP(rq[o][i]) }
  else       { WINLOOP(rq[o][j]) }
#undef WINLOOP

  // ---- epilogue: out = Wv * (xa / s) via fdot2 ----
  h2v xav2[OW][NCP];
  #pragma unroll
  for (int o = 0; o < OW; o++) {
    float inv = 1.0f / s[o];
    #pragma unroll
    for (int cp = 0; cp < NCP; cp++)
      xav2[o][cp] = __builtin_amdgcn_cvt_pkrtz(xa[o][2 * cp] * inv,
                                               xa[o][2 * cp + 1] * inv);
  }

  __builtin_amdgcn_s_setprio(0);   // drop priority before the store/drain phase

  const int h = h0 + ty;
  const int wbase = w0 + 2 * tx;
  #pragma unroll
  for (int c = 0; c < DH; c++) {
    float a0 = 0.f, a1 = 0.f;
    #pragma unroll
    for (int cp = 0; cp < NCP; cp++) {
      a0 = __builtin_amdgcn_fdot2(swv2[c * 4 + cp], xav2[0][cp], a0, false);
      a1 = __builtin_amdgcn_fdot2(swv2[c * 4 + cp], xav2[1][cp], a1, false);
    }
    *(float2*)(&out[((size_t)(b * CH + g * DH + c) * HH + h) * WW + wbase]) =
        make_float2(a0, a1);
  }
}

extern "C" void kernel_launch(void* const* d_in, const int* in_sizes, int n_in,
                              void* d_out, int out_size, void* d_ws, size_t ws_size,
                              hipStream_t stream) {
  const float* x    = (const float*)d_in[0];
  // d_in[1] = r, unused by the reference computation
  const float* wq   = (const float*)d_in[2];
  const float* wk   = (const float*)d_in[3];
  const float* wv   = (const float*)d_in[4];
  const float* relh = (const float*)d_in[5];
  const float* relw = (const float*)d_in[6];
  float* out = (float*)d_out;

  const int B = in_sizes[0] / (CH * HH * WW);   // 8
  dim3 grid(WW / TW, HH / TH, B * NG);          // 2 x 4 x 64 = 512 blocks
  dim3 block(16, 16, 1);                        // 256 threads = 4 waves
  saconv_kernel<<<grid, block, 0, stream>>>(x, wq, wk, wv, relh, relw, out);
}